// Round 1
// baseline (1750.091 us; speedup 1.0000x reference)
//
#include <hip/hip_runtime.h>

// LSTM (B=8192, T=256, input=1, H=64) + fc1(64->32,relu) + fc2(32->2), fp32.
// One block per 32-batch tile (256 blocks = 1/CU). All state on-chip:
//   W_hh^T in LDS [k][j] (row pad 258), x tile in LDS, h double-buffered in
//   LDS [u][b] (row pad 36), c in registers.
// Thread tiling: 256 thr; thread = (bgroup = tid>>5 -> 4 batches,
//                                   ugroup = tid&31 -> 2 hidden units, all 4 gates)
// => 32 fp32 accumulators, inner k-loop: 12 LDS dwords (broadcast/2-way) + 32 FMA.

#define BT 32      // batch tile per block
#define TT 256     // timesteps
#define WPAD 258   // W row pad (dwords)
#define HPAD 36    // h row pad (dwords), multiple of 4 for float4 alignment

#if __has_builtin(__builtin_amdgcn_exp2f)
#define EXP2F __builtin_amdgcn_exp2f
#else
#define EXP2F exp2f
#endif
#if __has_builtin(__builtin_amdgcn_rcpf)
#define RCPF __builtin_amdgcn_rcpf
#else
#define RCPF(x) (1.0f / (x))
#endif

__device__ __forceinline__ float sigm(float v) {
    return RCPF(1.0f + EXP2F(-1.44269504089f * v));
}
__device__ __forceinline__ float tanh_(float v) {
    // tanh(x) = 2*sigmoid(2x) - 1
    return 2.0f * RCPF(1.0f + EXP2F(-2.88539008178f * v)) - 1.0f;
}

__global__ __launch_bounds__(256, 1) void lstm_fused(
    const float* __restrict__ x,      // [B, T]
    const float* __restrict__ W_ih,   // [256]  (input size 1)
    const float* __restrict__ W_hh,   // [256][64]
    const float* __restrict__ b_ih,   // [256]
    const float* __restrict__ b_hh,   // [256]
    const float* __restrict__ fc1_w,  // [32][64]
    const float* __restrict__ fc1_b,  // [32]
    const float* __restrict__ fc2_w,  // [2][32]
    const float* __restrict__ fc2_b,  // [2]
    float* __restrict__ out)          // [B][2]
{
    extern __shared__ float smem[];
    float (*W_lds)[WPAD] = (float (*)[WPAD])smem;                    // [64][258]
    float (*x_lds)[TT]   = (float (*)[TT])(smem + 64 * WPAD);        // [32][256]
    float (*h_lds)[64][HPAD] =
        (float (*)[64][HPAD])(smem + 64 * WPAD + BT * TT);           // [2][64][36]

    const int tid = threadIdx.x;
    const int bb0 = (tid >> 5) << 2;   // batch offset in tile: 0,4,...,28
    const int u0  = (tid & 31) << 1;   // hidden-unit offset: 0,2,...,62
    const long long bBase = (long long)blockIdx.x * BT;

    // ---- stage W_hh transposed: W_lds[k][j] = W_hh[j][k] (coalesced global) ----
    for (int idx = tid; idx < 64 * 256; idx += 256) {
        int j = idx >> 6, k = idx & 63;
        W_lds[k][j] = W_hh[idx];
    }
    // ---- stage x tile (coalesced) ----
    for (int idx = tid; idx < BT * TT; idx += 256) {
        int b = idx >> 8, tt = idx & 255;
        x_lds[b][tt] = x[(bBase + b) * TT + tt];
    }
    // ---- zero h buffer 0 ----
    for (int idx = tid; idx < 64 * HPAD; idx += 256)
        ((float*)h_lds[0])[idx] = 0.0f;

    // ---- per-thread gate weights/biases for columns j = g*64 + u0 + uu ----
    float wih[4][2], bias[4][2];
#pragma unroll
    for (int g = 0; g < 4; ++g)
#pragma unroll
        for (int uu = 0; uu < 2; ++uu) {
            int j = g * 64 + u0 + uu;
            wih[g][uu]  = W_ih[j];
            bias[g][uu] = b_ih[j] + b_hh[j];
        }

    float c[4][2] = {};   // cell state, registers
    __syncthreads();

    int p = 0;
#pragma unroll 1
    for (int t = 0; t < TT; ++t) {
        // init accumulators with input contribution + bias
        float xv[4];
#pragma unroll
        for (int bb = 0; bb < 4; ++bb) xv[bb] = x_lds[bb0 + bb][t];

        float acc[4][4][2];  // [gate][bb][uu]
#pragma unroll
        for (int g = 0; g < 4; ++g)
#pragma unroll
            for (int bb = 0; bb < 4; ++bb)
#pragma unroll
                for (int uu = 0; uu < 2; ++uu)
                    acc[g][bb][uu] = xv[bb] * wih[g][uu] + bias[g][uu];

        // gates += h @ W_hh^T  (64-long dot products)
#pragma unroll 16
        for (int k = 0; k < 64; ++k) {
            const float4 hv = *(const float4*)&h_lds[p][k][bb0];
            const float2 wi = *(const float2*)&W_lds[k][u0];
            const float2 wf = *(const float2*)&W_lds[k][u0 + 64];
            const float2 wg = *(const float2*)&W_lds[k][u0 + 128];
            const float2 wo = *(const float2*)&W_lds[k][u0 + 192];
            const float hb[4] = {hv.x, hv.y, hv.z, hv.w};
#pragma unroll
            for (int bb = 0; bb < 4; ++bb) {
                acc[0][bb][0] += hb[bb] * wi.x;  acc[0][bb][1] += hb[bb] * wi.y;
                acc[1][bb][0] += hb[bb] * wf.x;  acc[1][bb][1] += hb[bb] * wf.y;
                acc[2][bb][0] += hb[bb] * wg.x;  acc[2][bb][1] += hb[bb] * wg.y;
                acc[3][bb][0] += hb[bb] * wo.x;  acc[3][bb][1] += hb[bb] * wo.y;
            }
        }

        // elementwise LSTM cell update (torch gate order i,f,g,o)
        float hn[4][2];
#pragma unroll
        for (int bb = 0; bb < 4; ++bb)
#pragma unroll
            for (int uu = 0; uu < 2; ++uu) {
                float iv = sigm(acc[0][bb][uu]);
                float fv = sigm(acc[1][bb][uu]);
                float gv = tanh_(acc[2][bb][uu]);
                float ov = sigm(acc[3][bb][uu]);
                float cc = fv * c[bb][uu] + iv * gv;
                c[bb][uu] = cc;
                hn[bb][uu] = ov * tanh_(cc);
            }

        // write new h (double buffer)
#pragma unroll
        for (int uu = 0; uu < 2; ++uu) {
            *(float4*)&h_lds[p ^ 1][u0 + uu][bb0] =
                make_float4(hn[0][uu], hn[1][uu], hn[2][uu], hn[3][uu]);
        }
        p ^= 1;
        __syncthreads();
    }

    // ---- tail: fc1 (relu) + fc2, h_T is in h_lds[0][u][b] (256 steps, even) ----
    if (tid < BT) {
        const int b = tid;
        float z[32];
#pragma unroll 4
        for (int u2 = 0; u2 < 32; ++u2) {
            float a = fc1_b[u2];
            for (int k = 0; k < 64; ++k)
                a += fc1_w[u2 * 64 + k] * h_lds[0][k][b];
            z[u2] = a > 0.0f ? a : 0.0f;
        }
        float o0 = fc2_b[0], o1 = fc2_b[1];
#pragma unroll
        for (int u2 = 0; u2 < 32; ++u2) {
            o0 += z[u2] * fc2_w[u2];
            o1 += z[u2] * fc2_w[32 + u2];
        }
        out[(bBase + b) * 2 + 0] = o0;
        out[(bBase + b) * 2 + 1] = o1;
    }
}

extern "C" void kernel_launch(void* const* d_in, const int* in_sizes, int n_in,
                              void* d_out, int out_size, void* d_ws, size_t ws_size,
                              hipStream_t stream) {
    const float* x     = (const float*)d_in[0];
    const float* W_ih  = (const float*)d_in[1];
    const float* W_hh  = (const float*)d_in[2];
    const float* b_ih  = (const float*)d_in[3];
    const float* b_hh  = (const float*)d_in[4];
    const float* fc1_w = (const float*)d_in[5];
    const float* fc1_b = (const float*)d_in[6];
    const float* fc2_w = (const float*)d_in[7];
    const float* fc2_b = (const float*)d_in[8];
    float* out = (float*)d_out;

    const size_t lds_bytes = (size_t)(64 * WPAD + BT * TT + 2 * 64 * HPAD) * sizeof(float);
    // opt-in for >64KB dynamic LDS (ignore error if not needed on this ROCm)
    (void)hipFuncSetAttribute((const void*)lstm_fused,
                              hipFuncAttributeMaxDynamicSharedMemorySize,
                              (int)lds_bytes);

    lstm_fused<<<dim3(8192 / BT), dim3(256), lds_bytes, stream>>>(
        x, W_ih, W_hh, b_ih, b_hh, fc1_w, fc1_b, fc2_w, fc2_b, out);
}

// Round 2
// 277.470 us; speedup vs baseline: 6.3073x; 6.3073x over previous
//
#include <hip/hip_runtime.h>

// LSTM (B=8192, T=256, in=1, H=64) + fc1(64->32,relu) + fc2(32->2).
// MFMA split-bf16 recurrent GEMM. 256 blocks x 512 threads (8 waves, 2/SIMD).
// Wave w = (mh = w>>2 batch-half, ub = w&3 unit-block). Per wave 4 C-tiles
// (gates i,f,g,o) of 16x16 -> all 4 gates of a cell land in one lane.
// W_hh^T hi/lo bf16 fragments live in registers; h hi/lo bf16 planes in LDS
// so A-fragments are ds_read_b128 pre-packed. c in registers. 1 barrier/step.

typedef __attribute__((ext_vector_type(8))) short bf16x8;
typedef __attribute__((ext_vector_type(4))) float f32x4;

#define TT 256
#define BT 32
#define XPAD 258   // x row pad (f32): bank-spread broadcast reads
#define HROW 72    // h row stride in bf16 (64+8 pad) = 144B, 16B-aligned

#if __has_builtin(__builtin_amdgcn_exp2f)
#define EXP2F __builtin_amdgcn_exp2f
#else
#define EXP2F exp2f
#endif
#if __has_builtin(__builtin_amdgcn_rcpf)
#define RCPF __builtin_amdgcn_rcpf
#else
#define RCPF(x) (1.0f / (x))
#endif

__device__ __forceinline__ float sigm(float v) {
    return RCPF(1.0f + EXP2F(-1.44269504089f * v));
}
__device__ __forceinline__ float tanh_(float v) {
    return 2.0f * RCPF(1.0f + EXP2F(-2.88539008178f * v)) - 1.0f;
}
__device__ __forceinline__ ushort f2bf(float f) {  // RNE f32 -> bf16 bits
    union { float f; unsigned u; } v; v.f = f;
    unsigned r = v.u + 0x7FFFu + ((v.u >> 16) & 1u);
    return (ushort)(r >> 16);
}
__device__ __forceinline__ float bf2f(ushort b) {
    union { unsigned u; float f; } v; v.u = ((unsigned)b) << 16;
    return v.f;
}

__global__ __launch_bounds__(512, 1) void lstm_mfma(
    const float* __restrict__ x,      // [B,T]
    const float* __restrict__ W_ih,   // [256]
    const float* __restrict__ W_hh,   // [256][64]
    const float* __restrict__ b_ih,   // [256]
    const float* __restrict__ b_hh,   // [256]
    const float* __restrict__ fc1_w,  // [32][64]
    const float* __restrict__ fc1_b,  // [32]
    const float* __restrict__ fc2_w,  // [2][32]
    const float* __restrict__ fc2_b,  // [2]
    float* __restrict__ out)          // [B][2]
{
    __shared__ float  x_lds[BT][XPAD];
    __shared__ ushort h_hi[2][BT][HROW];
    __shared__ ushort h_lo[2][BT][HROW];

    const int tid  = threadIdx.x;
    const int lane = tid & 63;
    const int wv   = tid >> 6;      // wave 0..7
    const int mh   = wv >> 2;       // batch half
    const int ub   = wv & 3;        // unit block
    const int l15  = lane & 15;
    const int l4   = lane >> 4;     // 0..3
    const int u    = ub * 16 + l15; // hidden unit this lane owns (C col)
    const long long bBase = (long long)blockIdx.x * BT;

    // ---- stage x tile (coalesced) ----
    for (int idx = tid; idx < BT * TT; idx += 512) {
        int b = idx >> 8, t = idx & 255;
        x_lds[b][t] = x[(bBase + b) * TT + t];
    }
    // ---- zero h buffer 0 ----
    for (int idx = tid; idx < BT * HROW; idx += 512) {
        ((ushort*)h_hi[0])[idx] = 0;
        ((ushort*)h_lo[0])[idx] = 0;
    }

    // ---- W_hh^T B-fragments, hi/lo bf16, resident in registers ----
    // B[k][n]: lane supplies n = u (tile col), k = kt*32 + l4*8 + j
    // B[k][n] = W_hh[g*64+u][k] -> 8 consecutive floats per fragment.
    bf16x8 Bhi[4][2], Blo[4][2];
#pragma unroll
    for (int g = 0; g < 4; ++g)
#pragma unroll
        for (int kt = 0; kt < 2; ++kt) {
            const float* src = W_hh + (g * 64 + u) * 64 + kt * 32 + l4 * 8;
#pragma unroll
            for (int j = 0; j < 8; ++j) {
                float f   = src[j];
                ushort hi = f2bf(f);
                Bhi[g][kt][j] = (short)hi;
                Blo[g][kt][j] = (short)f2bf(f - bf2f(hi));
            }
        }

    float wih[4], bias[4];
#pragma unroll
    for (int g = 0; g < 4; ++g) {
        wih[g]  = W_ih[g * 64 + u];
        bias[g] = b_ih[g * 64 + u] + b_hh[g * 64 + u];
    }

    float cst[4] = {0.f, 0.f, 0.f, 0.f};
    const int arow  = mh * 16 + l15;      // A-frag row this lane reads
    const int crow0 = mh * 16 + l4 * 4;   // first C row this lane owns

    __syncthreads();

    int p = 0;
#pragma unroll 1
    for (int t = 0; t < TT; ++t) {
        // acc init: x*W_ih + bias (broadcast LDS reads, bank-spread by XPAD)
        float xr[4];
#pragma unroll
        for (int j = 0; j < 4; ++j) xr[j] = x_lds[crow0 + j][t];

        f32x4 acc[4];
#pragma unroll
        for (int g = 0; g < 4; ++g)
#pragma unroll
            for (int j = 0; j < 4; ++j)
                acc[g][j] = xr[j] * wih[g] + bias[g];

        // A-fragments: pre-packed bf16 hi/lo straight from LDS
        const bf16x8 ah0 = *(const bf16x8*)&h_hi[p][arow][l4 * 8];
        const bf16x8 ah1 = *(const bf16x8*)&h_hi[p][arow][32 + l4 * 8];
        const bf16x8 al0 = *(const bf16x8*)&h_lo[p][arow][l4 * 8];
        const bf16x8 al1 = *(const bf16x8*)&h_lo[p][arow][32 + l4 * 8];

        // 24 MFMAs, gate-chains interleaved (acc[g] reused every 4 insts)
#pragma unroll
        for (int kt = 0; kt < 2; ++kt) {
            const bf16x8 ah = kt ? ah1 : ah0;
            const bf16x8 al = kt ? al1 : al0;
#pragma unroll
            for (int g = 0; g < 4; ++g)
                acc[g] = __builtin_amdgcn_mfma_f32_16x16x32_bf16(ah, Bhi[g][kt], acc[g], 0, 0, 0);
#pragma unroll
            for (int g = 0; g < 4; ++g)
                acc[g] = __builtin_amdgcn_mfma_f32_16x16x32_bf16(ah, Blo[g][kt], acc[g], 0, 0, 0);
#pragma unroll
            for (int g = 0; g < 4; ++g)
                acc[g] = __builtin_amdgcn_mfma_f32_16x16x32_bf16(al, Bhi[g][kt], acc[g], 0, 0, 0);
        }

        // cell update (torch gate order i,f,g,o); split h -> bf16 hi/lo
#pragma unroll
        for (int j = 0; j < 4; ++j) {
            float iv = sigm(acc[0][j]);
            float fv = sigm(acc[1][j]);
            float gv = tanh_(acc[2][j]);
            float ov = sigm(acc[3][j]);
            float cc = fv * cst[j] + iv * gv;
            cst[j]   = cc;
            float hh = ov * tanh_(cc);
            ushort hi = f2bf(hh);
            h_hi[p ^ 1][crow0 + j][u] = hi;
            h_lo[p ^ 1][crow0 + j][u] = f2bf(hh - bf2f(hi));
        }
        __syncthreads();
        p ^= 1;
    }

    // ---- tail: final h is in h_hi/h_lo[p] ----
    // fc1 + relu: 256 threads, (b, 4 outputs); z -> x_lds (x dead now)
    if (tid < 256) {
        const int b = tid >> 3, part = tid & 7;
#pragma unroll
        for (int q = 0; q < 4; ++q) {
            const int u2 = part * 4 + q;
            float a = fc1_b[u2];
            for (int k = 0; k < 64; ++k) {
                float hf = bf2f(h_hi[p][b][k]) + bf2f(h_lo[p][b][k]);
                a += fc1_w[u2 * 64 + k] * hf;
            }
            x_lds[b][u2] = a > 0.0f ? a : 0.0f;
        }
    }
    __syncthreads();
    // fc2: 64 threads, (b, output)
    if (tid < 64) {
        const int b = tid >> 1, o = tid & 1;
        float a = fc2_b[o];
#pragma unroll
        for (int u2 = 0; u2 < 32; ++u2)
            a += x_lds[b][u2] * fc2_w[o * 32 + u2];
        out[(bBase + b) * 2 + o] = a;
    }
}

extern "C" void kernel_launch(void* const* d_in, const int* in_sizes, int n_in,
                              void* d_out, int out_size, void* d_ws, size_t ws_size,
                              hipStream_t stream) {
    const float* x     = (const float*)d_in[0];
    const float* W_ih  = (const float*)d_in[1];
    const float* W_hh  = (const float*)d_in[2];
    const float* b_ih  = (const float*)d_in[3];
    const float* b_hh  = (const float*)d_in[4];
    const float* fc1_w = (const float*)d_in[5];
    const float* fc1_b = (const float*)d_in[6];
    const float* fc2_w = (const float*)d_in[7];
    const float* fc2_b = (const float*)d_in[8];
    float* out = (float*)d_out;

    lstm_mfma<<<dim3(8192 / BT), dim3(512), 0, stream>>>(
        x, W_ih, W_hh, b_ih, b_hh, fc1_w, fc1_b, fc2_w, fc2_b, out);
}

// Round 3
// 249.467 us; speedup vs baseline: 7.0153x; 1.1123x over previous
//
#include <hip/hip_runtime.h>

// LSTM (B=8192, T=256, in=1, H=64) + fc1(64->32,relu) + fc2(32->2).
// Transposed MFMA split-bf16: gates^T[256u][16b] = W_hh * h^T per block-step.
// 512 blocks x 256 thr (4 waves); 2 blocks/CU so barrier phases of one block
// overlap MFMA of the other. Wave = u-block (ub). Per wave 4 gate C-tiles
// 16x16 (i,f,g,o) -> lane owns (b = lane&15, u = ub*16+(lane>>4)*4 +0..3),
// all 4 gates lane-local. W hi/lo frags in registers; h hi/lo bf16 planes in
// LDS read as pre-packed ds_read_b128; h written as cvt_pk packed ds_write_b64.

typedef __attribute__((ext_vector_type(8))) short bf16x8;
typedef __attribute__((ext_vector_type(4))) float f32x4;

#define TT 256
#define BT 16
#define XPAD 260   // f32 row pad: 1040B rows, 16B aligned, 2-way-max banks
#define HROW 72    // h row stride in bf16 (64+8) = 144B

#if __has_builtin(__builtin_amdgcn_exp2f)
#define EXP2F __builtin_amdgcn_exp2f
#else
#define EXP2F exp2f
#endif
#if __has_builtin(__builtin_amdgcn_rcpf)
#define RCPF __builtin_amdgcn_rcpf
#else
#define RCPF(x) (1.0f / (x))
#endif

__device__ __forceinline__ float sigm(float v) {
    return RCPF(1.0f + EXP2F(-1.44269504089f * v));
}
__device__ __forceinline__ float tanh_(float v) {
    return 2.0f * RCPF(1.0f + EXP2F(-2.88539008178f * v)) - 1.0f;
}
__device__ __forceinline__ ushort f2bf(float f) {  // RNE f32 -> bf16 bits
    union { float f; unsigned u; } v; v.f = f;
    unsigned r = v.u + 0x7FFFu + ((v.u >> 16) & 1u);
    return (ushort)(r >> 16);
}
__device__ __forceinline__ float bf2f(ushort b) {
    union { unsigned u; float f; } v; v.u = ((unsigned)b) << 16;
    return v.f;
}
__device__ __forceinline__ float lo_as_f(unsigned pk) {  // low bf16 of pack
    union { unsigned u; float f; } v; v.u = pk << 16;
    return v.f;
}
__device__ __forceinline__ float hi_as_f(unsigned pk) {  // high bf16 of pack
    union { unsigned u; float f; } v; v.u = pk & 0xFFFF0000u;
    return v.f;
}
__device__ __forceinline__ unsigned cvt_pk(float a, float b) {  // lo=bf(a),hi=bf(b)
    unsigned r;
    asm("v_cvt_pk_bf16_f32 %0, %1, %2" : "=v"(r) : "v"(a), "v"(b));
    return r;
}

__global__ __launch_bounds__(256, 2) void lstm_mfma_t(
    const float* __restrict__ x,      // [B,T]
    const float* __restrict__ W_ih,   // [256]
    const float* __restrict__ W_hh,   // [256][64]
    const float* __restrict__ b_ih,   // [256]
    const float* __restrict__ b_hh,   // [256]
    const float* __restrict__ fc1_w,  // [32][64]
    const float* __restrict__ fc1_b,  // [32]
    const float* __restrict__ fc2_w,  // [2][32]
    const float* __restrict__ fc2_b,  // [2]
    float* __restrict__ out)          // [B][2]
{
    __shared__ float  x_lds[BT][XPAD];
    __shared__ ushort h_hi[2][BT][HROW];
    __shared__ ushort h_lo[2][BT][HROW];

    const int tid  = threadIdx.x;
    const int lane = tid & 63;
    const int ub   = tid >> 6;       // wave 0..3 = unit block
    const int l15  = lane & 15;      // batch b; also W-row within tile
    const int l4   = lane >> 4;      // 0..3
    const int u0   = ub * 16 + l4 * 4;  // first hidden unit this lane owns
    const long long bBase = (long long)blockIdx.x * BT;

    // ---- stage x tile via float4 (coalesced) ----
    {
        const float4* xg = (const float4*)(x + bBase * TT);
        for (int idx = tid; idx < BT * TT / 4; idx += 256) {
            int b = idx >> 6, c4 = idx & 63;
            *(float4*)&x_lds[b][c4 * 4] = xg[idx];
        }
    }
    // ---- zero h buffer 0 ----
    for (int idx = tid; idx < BT * HROW; idx += 256) {
        ((ushort*)h_hi[0])[idx] = 0;
        ((ushort*)h_lo[0])[idx] = 0;
    }

    // ---- W_hh A-fragments, hi/lo bf16, resident in registers ----
    // A[m][k]: m = l15 (row within tile, abs row g*64+ub*16+l15),
    //          k = kt*32 + l4*8 + j -> 8 consecutive floats.
    bf16x8 Whi[4][2], Wlo[4][2];
#pragma unroll
    for (int g = 0; g < 4; ++g)
#pragma unroll
        for (int kt = 0; kt < 2; ++kt) {
            const float* src = W_hh + (g * 64 + ub * 16 + l15) * 64 + kt * 32 + l4 * 8;
#pragma unroll
            for (int j = 0; j < 8; ++j) {
                float f   = src[j];
                ushort hi = f2bf(f);
                Whi[g][kt][j] = (short)hi;
                Wlo[g][kt][j] = (short)f2bf(f - bf2f(hi));
            }
        }

    // per-lane gate input weights / biases for u = u0+j
    float wih[4][4], bias[4][4];
#pragma unroll
    for (int g = 0; g < 4; ++g)
#pragma unroll
        for (int j = 0; j < 4; ++j) {
            int idx = g * 64 + u0 + j;
            wih[g][j]  = W_ih[idx];
            bias[g][j] = b_ih[idx] + b_hh[idx];
        }

    float cst[4] = {0.f, 0.f, 0.f, 0.f};
    __syncthreads();

    int p = 0;
#pragma unroll 1
    for (int t = 0; t < TT; ++t) {
        // acc init: x*W_ih + bias (x read is broadcast across l4 groups)
        const float xr = x_lds[l15][t];
        f32x4 acc[4];
#pragma unroll
        for (int g = 0; g < 4; ++g)
#pragma unroll
            for (int j = 0; j < 4; ++j)
                acc[g][j] = xr * wih[g][j] + bias[g][j];

        // B-fragments (h^T): pre-packed bf16 hi/lo straight from LDS
        const bf16x8 bh0 = *(const bf16x8*)&h_hi[p][l15][l4 * 8];
        const bf16x8 bh1 = *(const bf16x8*)&h_hi[p][l15][32 + l4 * 8];
        const bf16x8 bl0 = *(const bf16x8*)&h_lo[p][l15][l4 * 8];
        const bf16x8 bl1 = *(const bf16x8*)&h_lo[p][l15][32 + l4 * 8];

        // 24 MFMAs: Whi*hhi + Whi*hlo + Wlo*hhi, 4 gate-chains interleaved
#pragma unroll
        for (int kt = 0; kt < 2; ++kt) {
            const bf16x8 bh = kt ? bh1 : bh0;
            const bf16x8 bl = kt ? bl1 : bl0;
#pragma unroll
            for (int g = 0; g < 4; ++g)
                acc[g] = __builtin_amdgcn_mfma_f32_16x16x32_bf16(Whi[g][kt], bh, acc[g], 0, 0, 0);
#pragma unroll
            for (int g = 0; g < 4; ++g)
                acc[g] = __builtin_amdgcn_mfma_f32_16x16x32_bf16(Whi[g][kt], bl, acc[g], 0, 0, 0);
#pragma unroll
            for (int g = 0; g < 4; ++g)
                acc[g] = __builtin_amdgcn_mfma_f32_16x16x32_bf16(Wlo[g][kt], bh, acc[g], 0, 0, 0);
        }

        // cell update (torch gate order i,f,g,o)
        float hn[4];
#pragma unroll
        for (int j = 0; j < 4; ++j) {
            float iv = sigm(acc[0][j]);
            float fv = sigm(acc[1][j]);
            float gv = tanh_(acc[2][j]);
            float ov = sigm(acc[3][j]);
            float cc = fv * cst[j] + iv * gv;
            cst[j]   = cc;
            hn[j]    = ov * tanh_(cc);
        }

        // split h -> hi/lo, packed b64 stores (4 consecutive units per lane)
        unsigned hi01 = cvt_pk(hn[0], hn[1]);
        unsigned hi23 = cvt_pk(hn[2], hn[3]);
        unsigned lo01 = cvt_pk(hn[0] - lo_as_f(hi01), hn[1] - hi_as_f(hi01));
        unsigned lo23 = cvt_pk(hn[2] - lo_as_f(hi23), hn[3] - hi_as_f(hi23));
        *(uint2*)&h_hi[p ^ 1][l15][u0] = make_uint2(hi01, hi23);
        *(uint2*)&h_lo[p ^ 1][l15][u0] = make_uint2(lo01, lo23);

        __syncthreads();
        p ^= 1;
    }

    // ---- tail: fc1 + relu into x_lds (x dead), then fc2 ----
    for (int it = tid; it < BT * 32; it += 256) {
        const int b = it >> 5, u2 = it & 31;
        float a = fc1_b[u2];
        for (int k = 0; k < 64; ++k) {
            float hf = bf2f(h_hi[p][b][k]) + bf2f(h_lo[p][b][k]);
            a += fc1_w[u2 * 64 + k] * hf;
        }
        x_lds[b][u2] = a > 0.0f ? a : 0.0f;
    }
    __syncthreads();
    if (tid < BT * 2) {
        const int b = tid >> 1, o = tid & 1;
        float a = fc2_b[o];
#pragma unroll
        for (int u2 = 0; u2 < 32; ++u2)
            a += x_lds[b][u2] * fc2_w[o * 32 + u2];
        out[(bBase + b) * 2 + o] = a;
    }
}

extern "C" void kernel_launch(void* const* d_in, const int* in_sizes, int n_in,
                              void* d_out, int out_size, void* d_ws, size_t ws_size,
                              hipStream_t stream) {
    const float* x     = (const float*)d_in[0];
    const float* W_ih  = (const float*)d_in[1];
    const float* W_hh  = (const float*)d_in[2];
    const float* b_ih  = (const float*)d_in[3];
    const float* b_hh  = (const float*)d_in[4];
    const float* fc1_w = (const float*)d_in[5];
    const float* fc1_b = (const float*)d_in[6];
    const float* fc2_w = (const float*)d_in[7];
    const float* fc2_b = (const float*)d_in[8];
    float* out = (float*)d_out;

    lstm_mfma_t<<<dim3(8192 / BT), dim3(256), 0, stream>>>(
        x, W_ih, W_hh, b_ih, b_hh, fc1_w, fc1_b, fc2_w, fc2_b, out);
}